// Round 6
// baseline (299.727 us; speedup 1.0000x reference)
//
#include <hip/hip_runtime.h>
#include <stdint.h>

// ---------- helpers ----------
typedef __attribute__((ext_vector_type(8))) short bf16x8;
typedef __attribute__((ext_vector_type(4))) float f32x4;

__device__ __forceinline__ unsigned short f2bf(float f) {
  union { float f; unsigned u; } v; v.f = f;
  unsigned r = v.u + 0x7fffu + ((v.u >> 16) & 1u);   // RNE
  return (unsigned short)(r >> 16);
}
__device__ __forceinline__ float bf2f(unsigned short u) {
  union { unsigned u; float f; } v; v.u = ((unsigned)u) << 16; return v.f;
}
__device__ __forceinline__ void gload16(const void* g, void* l) {
  __builtin_amdgcn_global_load_lds(
      (const __attribute__((address_space(1))) unsigned int*)(uintptr_t)g,
      (__attribute__((address_space(3))) unsigned int*)(uintptr_t)l,
      16, 0, 0);
}

// ---------- kernel 1: gate + LN, one wave per row, no barriers ----------
// z rows interleaved: 2*row = book, 2*row+1 = iwslt
__global__ __launch_bounds__(256)
void k_gate_ln(const float* __restrict__ x, const int* __restrict__ dmask,
               const float* __restrict__ gw1, const float* __restrict__ gb1,
               const float* __restrict__ gw2, const float* __restrict__ gb2,
               const float* __restrict__ sb, const float* __restrict__ bb,
               const float* __restrict__ si, const float* __restrict__ bi,
               float* __restrict__ wout,          // [rows][4] f32: w0,w1,w2,0
               unsigned short* __restrict__ z)    // [2*rows][1024] bf16 interleaved
{
  const int lane = threadIdx.x & 63;
  const int row = blockIdx.x * 4 + (threadIdx.x >> 6);
  const float* xr = x + (size_t)row * 1024;

  float4 xv[4];
  float p0 = 0.f, p1 = 0.f, p2 = 0.f, p3 = 0.f, s = 0.f, ss = 0.f;
#pragma unroll
  for (int j = 0; j < 4; ++j) {
    const int i0 = lane * 4 + j * 256;
    xv[j] = *(const float4*)(xr + i0);
    const float xc[4] = {xv[j].x, xv[j].y, xv[j].z, xv[j].w};
#pragma unroll
    for (int c = 0; c < 4; ++c) {
      const float4 w = *(const float4*)(gw1 + (size_t)(i0 + c) * 4);
      p0 += xc[c] * w.x; p1 += xc[c] * w.y; p2 += xc[c] * w.z; p3 += xc[c] * w.w;
      s += xc[c]; ss += xc[c] * xc[c];
    }
  }
#pragma unroll
  for (int m = 32; m >= 1; m >>= 1) {
    p0 += __shfl_xor(p0, m, 64); p1 += __shfl_xor(p1, m, 64);
    p2 += __shfl_xor(p2, m, 64); p3 += __shfl_xor(p3, m, 64);
    s  += __shfl_xor(s,  m, 64); ss += __shfl_xor(ss, m, 64);
  }
  const float h0 = fmaxf(p0 + gb1[0], 0.f), h1 = fmaxf(p1 + gb1[1], 0.f);
  const float h2 = fmaxf(p2 + gb1[2], 0.f), h3 = fmaxf(p3 + gb1[3], 0.f);
  float lg[4];
#pragma unroll
  for (int e = 0; e < 4; ++e) {
    float val = h0 * gw2[e] + h1 * gw2[4 + e] + h2 * gw2[8 + e] + h3 * gw2[12 + e] + gb2[e];
    lg[e] = (dmask[e] == 0) ? -1.0e9f : val;
  }
  const float mx = fmaxf(fmaxf(lg[0], lg[1]), fmaxf(lg[2], lg[3]));
  const float e0 = expf(lg[0] - mx), e1 = expf(lg[1] - mx);
  const float e2 = expf(lg[2] - mx), e3 = expf(lg[3] - mx);
  const float inv = 1.f / (e0 + e1 + e2 + e3);
  if (lane == 0) {
    float4 wv; wv.x = e0 * inv; wv.y = e1 * inv; wv.z = e2 * inv; wv.w = 0.f;
    *(float4*)(wout + (size_t)row * 4) = wv;
  }
  const float mean = s * (1.f / 1024.f);
  const float rstd = rsqrtf(ss * (1.f / 1024.f) - mean * mean + 1e-6f);

#pragma unroll
  for (int j = 0; j < 4; ++j) {
    const int i0 = lane * 4 + j * 256;
    const float4 sbv = *(const float4*)(sb + i0);
    const float4 bbv = *(const float4*)(bb + i0);
    const float4 siv = *(const float4*)(si + i0);
    const float4 biv = *(const float4*)(bi + i0);
    const float xc[4] = {xv[j].x, xv[j].y, xv[j].z, xv[j].w};
    const float sbs[4] = {sbv.x, sbv.y, sbv.z, sbv.w};
    const float bbs[4] = {bbv.x, bbv.y, bbv.z, bbv.w};
    const float sis[4] = {siv.x, siv.y, siv.z, siv.w};
    const float bis[4] = {biv.x, biv.y, biv.z, biv.w};
    ushort4 zb, zi;
    unsigned short zbv[4], ziv[4];
#pragma unroll
    for (int c = 0; c < 4; ++c) {
      const float xn = (xc[c] - mean) * rstd;
      zbv[c] = f2bf(xn * sbs[c] + bbs[c]);
      ziv[c] = f2bf(xn * sis[c] + bis[c]);
    }
    zb.x = zbv[0]; zb.y = zbv[1]; zb.z = zbv[2]; zb.w = zbv[3];
    zi.x = ziv[0]; zi.y = ziv[1]; zi.z = ziv[2]; zi.w = ziv[3];
    *(ushort4*)(z + (size_t)(2 * row) * 1024 + i0) = zb;
    *(ushort4*)(z + (size_t)(2 * row + 1) * 1024 + i0) = zi;
  }
}

// ---------- kernel 2: f32 (R,C) -> bf16 transposed (C,R) ----------
__global__ __launch_bounds__(256)
void k_transpose_bf16(const float* __restrict__ src, unsigned short* __restrict__ dst,
                      int R, int C)
{
  __shared__ float tile[32][33];
  const int tx = threadIdx.x & 31, ty = threadIdx.x >> 5;
  const int c0 = blockIdx.x * 32, r0 = blockIdx.y * 32;
#pragma unroll
  for (int j = 0; j < 32; j += 8)
    tile[ty + j][tx] = src[(size_t)(r0 + ty + j) * C + c0 + tx];
  __syncthreads();
#pragma unroll
  for (int j = 0; j < 32; j += 8)
    dst[(size_t)(c0 + ty + j) * R + r0 + tx] = f2bf(tile[tx][ty + j]);
}

// ---------- kernel 3: 256x256 bf16 GEMM, 16 waves (4M x 4N, 64x64/wave) ----------
// acc[4][4]=64 VGPR -> <=128 total regs/thread -> 4 waves/SIMD (the overlap lever).
// MODE 0: C = relu(A@Bt^T + bias) -> bf16 (LDS-retiled coalesced store)
// MODE 1: fused mix epilogue (M interleaved book/iwslt pairs)
template <int MODE, int K, int NBX>
__global__ __launch_bounds__(1024, 4)
void gemm256(const unsigned short* __restrict__ A,
             const unsigned short* __restrict__ Bt,
             const float* __restrict__ bias,
             unsigned short* __restrict__ Cb,
             const float* __restrict__ x,
             const float* __restrict__ wgt,
             float* __restrict__ outp)
{
  constexpr int NKT = K / 64;
  constexpr int N = NBX * 256;
  __shared__ __align__(16) char lds[131072];

  const int tid = threadIdx.x;
  const int wave = tid >> 6, lane = tid & 63;
  const int lr = lane & 15, lk = lane >> 4;
  const int wm = wave >> 2, wn = wave & 3;

  // XCD-aware bijective block swizzle (gridDim.x % 8 == 0)
  const int cpx = (int)gridDim.x >> 3;
  const int flat = (int)blockIdx.x;
  const int swz = (flat & 7) * cpx + (flat >> 3);
  const int bm0 = (swz / NBX) * 256;
  const int bn0 = (swz % NBX) * 256;

  // staging: inverse-swizzled global source, linear LDS dest (rule #21)
  const int srow = tid >> 3;                       // 0..127
  const int schunk = ((tid & 7) ^ (srow & 7)) * 8; // element offset
  const unsigned short* aSrc = A + (size_t)(bm0 + srow) * K + schunk;
  const unsigned short* bSrc = Bt + (size_t)(bn0 + srow) * K + schunk;

  // read-side swizzled k-offsets (verified: 0 bank conflicts)
  const int xorv = (lr & 7) << 4;
  const int koff0 = (lk * 16) ^ xorv;
  const int koff1 = (64 + lk * 16) ^ xorv;
  const int arow = wm * 64 + lr;
  const int brow = wn * 64 + lr;

  f32x4 acc[4][4] = {};

  // per tile: A rows 0-127,128-255 then B rows; 4 gloads/thread (64KB/tile)
  auto stage_tile = [&](int tt) {
    char* dbase = lds + ((tt & 1) << 16);
#pragma unroll
    for (int r = 0; r < 2; ++r) {
      gload16(aSrc + (size_t)(r * 128) * K + tt * 64, dbase + r * 16384 + wave * 1024);
      gload16(bSrc + (size_t)(r * 128) * K + tt * 64, dbase + 32768 + r * 16384 + wave * 1024);
    }
  };

  stage_tile(0);
  asm volatile("s_waitcnt vmcnt(0)" ::: "memory");
  __builtin_amdgcn_s_barrier();

#pragma unroll 2
  for (int t = 0; t < NKT; ++t) {
    const char* curA = lds + ((t & 1) << 16);
    const char* curB = curA + 32768;
    if (t + 1 < NKT) stage_tile(t + 1);

    bf16x8 bfr[4], afr[4];
    // k-half 0
#pragma unroll
    for (int ni = 0; ni < 4; ++ni)
      bfr[ni] = *(const bf16x8*)(curB + (brow + ni * 16) * 128 + koff0);
#pragma unroll
    for (int mi = 0; mi < 4; ++mi)
      afr[mi] = *(const bf16x8*)(curA + (arow + mi * 16) * 128 + koff0);
    __builtin_amdgcn_s_setprio(1);
#pragma unroll
    for (int mi = 0; mi < 4; ++mi)
#pragma unroll
      for (int ni = 0; ni < 4; ++ni)
        acc[mi][ni] = __builtin_amdgcn_mfma_f32_16x16x32_bf16(afr[mi], bfr[ni], acc[mi][ni], 0, 0, 0);
    __builtin_amdgcn_s_setprio(0);
    // k-half 1
#pragma unroll
    for (int ni = 0; ni < 4; ++ni)
      bfr[ni] = *(const bf16x8*)(curB + (brow + ni * 16) * 128 + koff1);
#pragma unroll
    for (int mi = 0; mi < 4; ++mi)
      afr[mi] = *(const bf16x8*)(curA + (arow + mi * 16) * 128 + koff1);
    __builtin_amdgcn_s_setprio(1);
#pragma unroll
    for (int mi = 0; mi < 4; ++mi)
#pragma unroll
      for (int ni = 0; ni < 4; ++ni)
        acc[mi][ni] = __builtin_amdgcn_mfma_f32_16x16x32_bf16(afr[mi], bfr[ni], acc[mi][ni], 0, 0, 0);
    __builtin_amdgcn_s_setprio(0);

    asm volatile("s_waitcnt vmcnt(0)" ::: "memory");
    __builtin_amdgcn_s_barrier();
  }

  __syncthreads();   // LDS reuse for epilogue retile

  if (MODE == 0) {
    // bf16 tile [256 rows][512B] = 128KB, swizzle byte ^= (row&7)<<4
#pragma unroll
    for (int ni = 0; ni < 4; ++ni) {
      const int col = wn * 64 + ni * 16 + lr;
      const float bv = bias[bn0 + col];
#pragma unroll
      for (int mi = 0; mi < 4; ++mi) {
#pragma unroll
        for (int j = 0; j < 4; ++j) {
          const int row = wm * 64 + mi * 16 + lk * 4 + j;
          float v = fmaxf(acc[mi][ni][j] + bv, 0.f);
          *(unsigned short*)(lds + row * 512 + ((col * 2) ^ ((row & 7) << 4))) = f2bf(v);
        }
      }
    }
    __syncthreads();
#pragma unroll
    for (int sx = 0; sx < 8; ++sx) {
      const int row = wave * 16 + sx * 2 + (lane >> 5);
      const int c = lane & 31;
      bf16x8 vv = *(const bf16x8*)(lds + row * 512 + ((c * 16) ^ ((row & 7) << 4)));
      *(bf16x8*)(Cb + (size_t)(bm0 + row) * N + bn0 + c * 8) = vv;
    }
  } else {
    // mix epilogue: f32 tile [128 orows][1024B] = 128KB, swizzle ^= (lrow&6)<<5
    const int orbase = bm0 >> 1;
#pragma unroll
    for (int mi = 0; mi < 4; ++mi) {
      const int lr0 = wm * 32 + mi * 8 + lk * 2;
      const float4 wa = *(const float4*)(wgt + (size_t)(orbase + lr0) * 4);
      const float4 wb = *(const float4*)(wgt + (size_t)(orbase + lr0 + 1) * 4);
#pragma unroll
      for (int ni = 0; ni < 4; ++ni) {
        const int colb = (wn * 64 + ni * 16 + lr) * 4;
        const float bv = bias[bn0 + wn * 64 + ni * 16 + lr];
        float m0 = wa.y * (acc[mi][ni][0] + bv) + wa.z * (acc[mi][ni][1] + bv);
        float m1 = wb.y * (acc[mi][ni][2] + bv) + wb.z * (acc[mi][ni][3] + bv);
        *(float*)(lds + (size_t)lr0 * 1024 + (colb ^ ((lr0 & 6) << 5))) = m0;
        *(float*)(lds + (size_t)(lr0 + 1) * 1024 + (colb ^ (((lr0 + 1) & 6) << 5))) = m1;
      }
    }
    __syncthreads();
#pragma unroll
    for (int sx = 0; sx < 8; ++sx) {
      const int lrow = wave * 8 + sx;
      const int gor = orbase + lrow;
      f32x4 m = *(const f32x4*)(lds + (size_t)lrow * 1024 + ((lane * 16) ^ ((lrow & 6) << 5)));
      const float4 xv = *(const float4*)(x + (size_t)gor * 1024 + bn0 + lane * 4);
      const float w0 = wgt[(size_t)gor * 4];
      f32x4 o;
      o[0] = xv.x * (1.f + w0) + m[0];
      o[1] = xv.y * (1.f + w0) + m[1];
      o[2] = xv.z * (1.f + w0) + m[2];
      o[3] = xv.w * (1.f + w0) + m[3];
      *(f32x4*)(outp + (size_t)gor * 1024 + bn0 + lane * 4) = o;
    }
  }
}

// ---------- launch ----------
extern "C" void kernel_launch(void* const* d_in, const int* in_sizes, int n_in,
                              void* d_out, int out_size, void* d_ws, size_t ws_size,
                              hipStream_t stream) {
  const float* x    = (const float*)d_in[0];
  const int*   dm   = (const int*)  d_in[1];
  const float* gw1  = (const float*)d_in[2];
  const float* gb1  = (const float*)d_in[3];
  const float* gw2  = (const float*)d_in[4];
  const float* gb2  = (const float*)d_in[5];
  const float* lsb  = (const float*)d_in[6];
  const float* lbb  = (const float*)d_in[7];
  const float* lsi  = (const float*)d_in[8];
  const float* lbi  = (const float*)d_in[9];
  const float* aw1  = (const float*)d_in[10];
  const float* ab1  = (const float*)d_in[11];
  const float* aw2  = (const float*)d_in[12];
  const float* ab2  = (const float*)d_in[13];
  float* out = (float*)d_out;

  char* ws = (char*)d_ws;
  float*          wgt  = (float*)(ws + 0);                                     // 128KB
  unsigned short* z    = (unsigned short*)(ws + 131072);                       // 32MB (interleaved)
  unsigned short* w1t  = (unsigned short*)(ws + 131072 + 33554432);            // 4MB
  unsigned short* w2t  = (unsigned short*)(ws + 131072 + 33554432 + 4194304);  // 4MB
  unsigned short* hbuf = (unsigned short*)(ws + 131072 + 33554432 + 8388608);  // 64MB

  k_gate_ln<<<2048, 256, 0, stream>>>(x, dm, gw1, gb1, gw2, gb2,
                                      lsb, lbb, lsi, lbi, wgt, z);
  k_transpose_bf16<<<dim3(2048/32, 1024/32), 256, 0, stream>>>(aw1, w1t, 1024, 2048);
  k_transpose_bf16<<<dim3(1024/32, 2048/32), 256, 0, stream>>>(aw2, w2t, 2048, 1024);
  // GEMM1: h = relu(z @ w1 + b1)   [16384 x 2048], K=1024
  gemm256<0, 1024, 8><<<512, 1024, 0, stream>>>(z, w1t, ab1, hbuf, nullptr, nullptr, nullptr);
  // GEMM2 (+fused mix): out = x*(1+w0) + w1*ab + w2*ai   [rows 8192 x 1024], K=2048
  gemm256<1, 2048, 4><<<256, 1024, 0, stream>>>(hbuf, w2t, ab2, nullptr, x, wgt, out);
}

// Round 7
// 254.091 us; speedup vs baseline: 1.1796x; 1.1796x over previous
//
#include <hip/hip_runtime.h>
#include <stdint.h>

// ---------- helpers ----------
typedef __attribute__((ext_vector_type(8))) short bf16x8;
typedef __attribute__((ext_vector_type(4))) float f32x4;

__device__ __forceinline__ unsigned short f2bf(float f) {
  union { float f; unsigned u; } v; v.f = f;
  unsigned r = v.u + 0x7fffu + ((v.u >> 16) & 1u);   // RNE
  return (unsigned short)(r >> 16);
}
__device__ __forceinline__ float bf2f(unsigned short u) {
  union { unsigned u; float f; } v; v.u = ((unsigned)u) << 16; return v.f;
}
__device__ __forceinline__ void gload16(const void* g, void* l) {
  __builtin_amdgcn_global_load_lds(
      (const __attribute__((address_space(1))) unsigned int*)(uintptr_t)g,
      (__attribute__((address_space(3))) unsigned int*)(uintptr_t)l,
      16, 0, 0);
}

// ---------- kernel 1: gate + LN, one wave per row, no barriers ----------
// z rows interleaved: 2*row = book, 2*row+1 = iwslt
__global__ __launch_bounds__(256)
void k_gate_ln(const float* __restrict__ x, const int* __restrict__ dmask,
               const float* __restrict__ gw1, const float* __restrict__ gb1,
               const float* __restrict__ gw2, const float* __restrict__ gb2,
               const float* __restrict__ sb, const float* __restrict__ bb,
               const float* __restrict__ si, const float* __restrict__ bi,
               float* __restrict__ wout,          // [rows][4] f32: w0,w1,w2,0
               unsigned short* __restrict__ z)    // [2*rows][1024] bf16 interleaved
{
  const int lane = threadIdx.x & 63;
  const int row = blockIdx.x * 4 + (threadIdx.x >> 6);
  const float* xr = x + (size_t)row * 1024;

  float4 xv[4];
  float p0 = 0.f, p1 = 0.f, p2 = 0.f, p3 = 0.f, s = 0.f, ss = 0.f;
#pragma unroll
  for (int j = 0; j < 4; ++j) {
    const int i0 = lane * 4 + j * 256;
    xv[j] = *(const float4*)(xr + i0);
    const float xc[4] = {xv[j].x, xv[j].y, xv[j].z, xv[j].w};
#pragma unroll
    for (int c = 0; c < 4; ++c) {
      const float4 w = *(const float4*)(gw1 + (size_t)(i0 + c) * 4);
      p0 += xc[c] * w.x; p1 += xc[c] * w.y; p2 += xc[c] * w.z; p3 += xc[c] * w.w;
      s += xc[c]; ss += xc[c] * xc[c];
    }
  }
#pragma unroll
  for (int m = 32; m >= 1; m >>= 1) {
    p0 += __shfl_xor(p0, m, 64); p1 += __shfl_xor(p1, m, 64);
    p2 += __shfl_xor(p2, m, 64); p3 += __shfl_xor(p3, m, 64);
    s  += __shfl_xor(s,  m, 64); ss += __shfl_xor(ss, m, 64);
  }
  const float h0 = fmaxf(p0 + gb1[0], 0.f), h1 = fmaxf(p1 + gb1[1], 0.f);
  const float h2 = fmaxf(p2 + gb1[2], 0.f), h3 = fmaxf(p3 + gb1[3], 0.f);
  float lg[4];
#pragma unroll
  for (int e = 0; e < 4; ++e) {
    float val = h0 * gw2[e] + h1 * gw2[4 + e] + h2 * gw2[8 + e] + h3 * gw2[12 + e] + gb2[e];
    lg[e] = (dmask[e] == 0) ? -1.0e9f : val;
  }
  const float mx = fmaxf(fmaxf(lg[0], lg[1]), fmaxf(lg[2], lg[3]));
  const float e0 = expf(lg[0] - mx), e1 = expf(lg[1] - mx);
  const float e2 = expf(lg[2] - mx), e3 = expf(lg[3] - mx);
  const float inv = 1.f / (e0 + e1 + e2 + e3);
  if (lane == 0) {
    float4 wv; wv.x = e0 * inv; wv.y = e1 * inv; wv.z = e2 * inv; wv.w = 0.f;
    *(float4*)(wout + (size_t)row * 4) = wv;
  }
  const float mean = s * (1.f / 1024.f);
  const float rstd = rsqrtf(ss * (1.f / 1024.f) - mean * mean + 1e-6f);

#pragma unroll
  for (int j = 0; j < 4; ++j) {
    const int i0 = lane * 4 + j * 256;
    const float4 sbv = *(const float4*)(sb + i0);
    const float4 bbv = *(const float4*)(bb + i0);
    const float4 siv = *(const float4*)(si + i0);
    const float4 biv = *(const float4*)(bi + i0);
    const float xc[4] = {xv[j].x, xv[j].y, xv[j].z, xv[j].w};
    const float sbs[4] = {sbv.x, sbv.y, sbv.z, sbv.w};
    const float bbs[4] = {bbv.x, bbv.y, bbv.z, bbv.w};
    const float sis[4] = {siv.x, siv.y, siv.z, siv.w};
    const float bis[4] = {biv.x, biv.y, biv.z, biv.w};
    ushort4 zb, zi;
    unsigned short zbv[4], ziv[4];
#pragma unroll
    for (int c = 0; c < 4; ++c) {
      const float xn = (xc[c] - mean) * rstd;
      zbv[c] = f2bf(xn * sbs[c] + bbs[c]);
      ziv[c] = f2bf(xn * sis[c] + bis[c]);
    }
    zb.x = zbv[0]; zb.y = zbv[1]; zb.z = zbv[2]; zb.w = zbv[3];
    zi.x = ziv[0]; zi.y = ziv[1]; zi.z = ziv[2]; zi.w = ziv[3];
    *(ushort4*)(z + (size_t)(2 * row) * 1024 + i0) = zb;
    *(ushort4*)(z + (size_t)(2 * row + 1) * 1024 + i0) = zi;
  }
}

// ---------- kernel 2: f32 (R,C) -> bf16 transposed (C,R) ----------
__global__ __launch_bounds__(256)
void k_transpose_bf16(const float* __restrict__ src, unsigned short* __restrict__ dst,
                      int R, int C)
{
  __shared__ float tile[32][33];
  const int tx = threadIdx.x & 31, ty = threadIdx.x >> 5;
  const int c0 = blockIdx.x * 32, r0 = blockIdx.y * 32;
#pragma unroll
  for (int j = 0; j < 32; j += 8)
    tile[ty + j][tx] = src[(size_t)(r0 + ty + j) * C + c0 + tx];
  __syncthreads();
#pragma unroll
  for (int j = 0; j < 32; j += 8)
    dst[(size_t)(c0 + ty + j) * R + r0 + tx] = f2bf(tile[tx][ty + j]);
}

// ---------- kernel 3: 256x256 bf16 GEMM, 8 waves (2Mx4N, 128x64/wave) ----------
// Anti-phase k-halves: even waves do half0 then half1, odd waves half1 then half0.
// Both halves are read-only in the current buffer -> no sync change; the two waves
// on each SIMD run read-cluster vs MFMA-cluster in opposite phases (pipe overlap).
// MODE 0: C = relu(A@Bt^T + bias) -> bf16 (LDS-retiled coalesced store)
// MODE 1: fused mix epilogue (M interleaved book/iwslt pairs)
template <int MODE, int K, int NBX>
__global__ __launch_bounds__(512, 2)
void gemm256(const unsigned short* __restrict__ A,
             const unsigned short* __restrict__ Bt,
             const float* __restrict__ bias,
             unsigned short* __restrict__ Cb,
             const float* __restrict__ x,
             const float* __restrict__ wgt,
             float* __restrict__ outp)
{
  constexpr int NKT = K / 64;
  constexpr int N = NBX * 256;
  __shared__ __align__(16) char lds[131072];

  const int tid = threadIdx.x;
  const int wave = tid >> 6, lane = tid & 63;
  const int lr = lane & 15, lk = lane >> 4;
  const int wm = wave >> 2, wn = wave & 3;

  // XCD-aware bijective block swizzle (gridDim.x % 8 == 0)
  const int cpx = (int)gridDim.x >> 3;
  const int flat = (int)blockIdx.x;
  const int swz = (flat & 7) * cpx + (flat >> 3);
  const int bm0 = (swz / NBX) * 256;
  const int bn0 = (swz % NBX) * 256;

  // staging: inverse-swizzled global source, linear LDS dest (rule #21)
  const int srow = tid >> 3;
  const int schunk = ((tid & 7) ^ (srow & 7)) * 8;
  const unsigned short* aSrc = A + (size_t)(bm0 + srow) * K + schunk;
  const unsigned short* bSrc = Bt + (size_t)(bn0 + srow) * K + schunk;
  const int ldsWaveOff = wave * 1024;

  // read-side swizzled k-offsets (verified: 0 bank conflicts)
  const int xorv = (lr & 7) << 4;
  const int koff0 = (lk * 16) ^ xorv;
  const int koff1 = (64 + lk * 16) ^ xorv;
  // anti-phase: wave parity picks half order
  const int kA = (wave & 1) ? koff1 : koff0;
  const int kB = (wave & 1) ? koff0 : koff1;
  const int arowB = wm * 128 + lr;
  const int browB = wn * 64 + lr;

  f32x4 acc[8][4] = {};

  auto stage_tile = [&](int tt) {
#pragma unroll
    for (int h = 0; h < 4; ++h) {   // {B-lo, B-hi, A-lo, A-hi}
      const unsigned short* sp = (h < 2 ? bSrc : aSrc) + (size_t)((h & 1) * 128) * K + tt * 64;
      char* d = lds + ((tt & 1) << 16) + ((h < 2) ? 32768 : 0) + ((h & 1) << 14) + ldsWaveOff;
      gload16(sp, d);
      gload16(sp + (size_t)64 * K, d + 8192);
    }
  };

  stage_tile(0);
  asm volatile("s_waitcnt vmcnt(0)" ::: "memory");
  __builtin_amdgcn_s_barrier();

#pragma unroll 2
  for (int t = 0; t < NKT; ++t) {
    const char* curA = lds + ((t & 1) << 16);
    const char* curB = curA + 32768;
    if (t + 1 < NKT) stage_tile(t + 1);   // issue next tile's 8 gloads early

    // ---- half cluster 1 (own phase) ----
    {
      bf16x8 bf[4], af[8];
#pragma unroll
      for (int ni = 0; ni < 4; ++ni)
        bf[ni] = *(const bf16x8*)(curB + (browB + ni * 16) * 128 + kA);
#pragma unroll
      for (int mi = 0; mi < 8; ++mi)
        af[mi] = *(const bf16x8*)(curA + (arowB + mi * 16) * 128 + kA);
      __builtin_amdgcn_s_setprio(1);
#pragma unroll
      for (int mi = 0; mi < 8; ++mi)
#pragma unroll
        for (int ni = 0; ni < 4; ++ni)
          acc[mi][ni] = __builtin_amdgcn_mfma_f32_16x16x32_bf16(af[mi], bf[ni], acc[mi][ni], 0, 0, 0);
      __builtin_amdgcn_s_setprio(0);
    }
    // ---- half cluster 2 (opposite phase) ----
    {
      bf16x8 bf[4], af[8];
#pragma unroll
      for (int ni = 0; ni < 4; ++ni)
        bf[ni] = *(const bf16x8*)(curB + (browB + ni * 16) * 128 + kB);
#pragma unroll
      for (int mi = 0; mi < 8; ++mi)
        af[mi] = *(const bf16x8*)(curA + (arowB + mi * 16) * 128 + kB);
      __builtin_amdgcn_s_setprio(1);
#pragma unroll
      for (int mi = 0; mi < 8; ++mi)
#pragma unroll
        for (int ni = 0; ni < 4; ++ni)
          acc[mi][ni] = __builtin_amdgcn_mfma_f32_16x16x32_bf16(af[mi], bf[ni], acc[mi][ni], 0, 0, 0);
      __builtin_amdgcn_s_setprio(0);
    }

    asm volatile("s_waitcnt vmcnt(0)" ::: "memory");   // next tile landed (issued a tile ago)
    __builtin_amdgcn_s_barrier();
  }

  __syncthreads();   // LDS reuse for epilogue retile

  if (MODE == 0) {
    // bf16 tile [256 rows][512B], swizzle byte ^= (row&7)<<4 (<=2-way, free)
#pragma unroll
    for (int ni = 0; ni < 4; ++ni) {
      const int colb = (wn * 64 + ni * 16 + lr) * 2;
      const float bv = bias[bn0 + wn * 64 + ni * 16 + lr];
#pragma unroll
      for (int mi = 0; mi < 8; ++mi) {
#pragma unroll
        for (int j = 0; j < 4; ++j) {
          const int row = wm * 128 + mi * 16 + lk * 4 + j;
          float v = fmaxf(acc[mi][ni][j] + bv, 0.f);
          *(unsigned short*)(lds + row * 512 + (colb ^ ((row & 7) << 4))) = f2bf(v);
        }
      }
    }
    __syncthreads();
#pragma unroll
    for (int sx = 0; sx < 16; ++sx) {
      const int row = wave * 32 + sx * 2 + (lane >> 5);
      const int c = lane & 31;
      bf16x8 vv = *(const bf16x8*)(lds + row * 512 + ((c * 16) ^ ((row & 7) << 4)));
      *(bf16x8*)(Cb + (size_t)(bm0 + row) * N + bn0 + c * 8) = vv;
    }
  } else {
    // mix epilogue: f32 tile [128 orows][1024B], swizzle byte ^= (lrow&6)<<5 (<=2-way)
    const int orbase = bm0 >> 1;
#pragma unroll
    for (int mi = 0; mi < 8; ++mi) {
      const int lr0 = wm * 64 + mi * 8 + lk * 2;
      const float4 wa = *(const float4*)(wgt + (size_t)(orbase + lr0) * 4);
      const float4 wb = *(const float4*)(wgt + (size_t)(orbase + lr0 + 1) * 4);
#pragma unroll
      for (int ni = 0; ni < 4; ++ni) {
        const int colb = (wn * 64 + ni * 16 + lr) * 4;
        const float bv = bias[bn0 + wn * 64 + ni * 16 + lr];
        float m0 = wa.y * (acc[mi][ni][0] + bv) + wa.z * (acc[mi][ni][1] + bv);
        float m1 = wb.y * (acc[mi][ni][2] + bv) + wb.z * (acc[mi][ni][3] + bv);
        *(float*)(lds + (size_t)lr0 * 1024 + (colb ^ ((lr0 & 6) << 5))) = m0;
        *(float*)(lds + (size_t)(lr0 + 1) * 1024 + (colb ^ (((lr0 + 1) & 6) << 5))) = m1;
      }
    }
    __syncthreads();
#pragma unroll
    for (int sx = 0; sx < 16; ++sx) {
      const int lrow = wave * 16 + sx;
      const int gor = orbase + lrow;
      f32x4 m = *(const f32x4*)(lds + (size_t)lrow * 1024 + ((lane * 16) ^ ((lrow & 6) << 5)));
      const float4 xv = *(const float4*)(x + (size_t)gor * 1024 + bn0 + lane * 4);
      const float w0 = wgt[(size_t)gor * 4];
      f32x4 o;
      o[0] = xv.x * (1.f + w0) + m[0];
      o[1] = xv.y * (1.f + w0) + m[1];
      o[2] = xv.z * (1.f + w0) + m[2];
      o[3] = xv.w * (1.f + w0) + m[3];
      *(f32x4*)(outp + (size_t)gor * 1024 + bn0 + lane * 4) = o;
    }
  }
}

// ---------- launch ----------
extern "C" void kernel_launch(void* const* d_in, const int* in_sizes, int n_in,
                              void* d_out, int out_size, void* d_ws, size_t ws_size,
                              hipStream_t stream) {
  const float* x    = (const float*)d_in[0];
  const int*   dm   = (const int*)  d_in[1];
  const float* gw1  = (const float*)d_in[2];
  const float* gb1  = (const float*)d_in[3];
  const float* gw2  = (const float*)d_in[4];
  const float* gb2  = (const float*)d_in[5];
  const float* lsb  = (const float*)d_in[6];
  const float* lbb  = (const float*)d_in[7];
  const float* lsi  = (const float*)d_in[8];
  const float* lbi  = (const float*)d_in[9];
  const float* aw1  = (const float*)d_in[10];
  const float* ab1  = (const float*)d_in[11];
  const float* aw2  = (const float*)d_in[12];
  const float* ab2  = (const float*)d_in[13];
  float* out = (float*)d_out;

  char* ws = (char*)d_ws;
  float*          wgt  = (float*)(ws + 0);                                     // 128KB
  unsigned short* z    = (unsigned short*)(ws + 131072);                       // 32MB (interleaved)
  unsigned short* w1t  = (unsigned short*)(ws + 131072 + 33554432);            // 4MB
  unsigned short* w2t  = (unsigned short*)(ws + 131072 + 33554432 + 4194304);  // 4MB
  unsigned short* hbuf = (unsigned short*)(ws + 131072 + 33554432 + 8388608);  // 64MB

  k_gate_ln<<<2048, 256, 0, stream>>>(x, dm, gw1, gb1, gw2, gb2,
                                      lsb, lbb, lsi, lbi, wgt, z);
  k_transpose_bf16<<<dim3(2048/32, 1024/32), 256, 0, stream>>>(aw1, w1t, 1024, 2048);
  k_transpose_bf16<<<dim3(1024/32, 2048/32), 256, 0, stream>>>(aw2, w2t, 2048, 1024);
  // GEMM1: h = relu(z @ w1 + b1)   [16384 x 2048], K=1024
  gemm256<0, 1024, 8><<<512, 512, 0, stream>>>(z, w1t, ab1, hbuf, nullptr, nullptr, nullptr);
  // GEMM2 (+fused mix): out = x*(1+w0) + w1*ab + w2*ai   [rows 8192 x 1024], K=2048
  gemm256<1, 2048, 4><<<256, 512, 0, stream>>>(hbuf, w2t, ab2, nullptr, x, wgt, out);
}